// Round 17
// baseline (68.952 us; speedup 1.0000x reference)
//
#include <hip/hip_runtime.h>

typedef unsigned int   uint_;
typedef unsigned short u16;
typedef _Float16 f16;
typedef __attribute__((ext_vector_type(8))) _Float16 f16x8;  // MFMA A/B frag
typedef __attribute__((ext_vector_type(2))) __fp16 h2;       // builtin half2
typedef __attribute__((ext_vector_type(4))) float f4;

// Problem constants
#define B_    8
#define CIN_  64
#define H_    128
#define W_    128
#define OC_   128
#define HO_   64
#define WO_   64
#define NPOS  (B_ * HO_ * WO_)   // 32768

// ws layout (float offsets)
#define XBT_OFF  0          // f16 x_bt (B,H,W,64) = 4194304 floats
#define MF_OFF   4194304    // u16[4096]  (f16 M frags, pre-scaled by log2e)
#define WF_OFF   4196352    // u16[16384] (f16 Wv frags)
#define WPOS_OFF 4204544    // packed h2: wp0[25] @ +0, wp1[25] @ +32 (u32 each)

// ---------------------------------------------------------------------------
// helpers
// ---------------------------------------------------------------------------
__device__ __forceinline__ u16 f2h_bits(float x) {
  return __builtin_bit_cast(u16, (f16)x);
}
__device__ __forceinline__ uint_ cvt_pk_u(float lo, float hi) {
  return __builtin_bit_cast(uint_, __builtin_amdgcn_cvt_pkrtz(lo, hi));
}
template <int N>
__device__ __forceinline__ float ror_add(float x) {
  float r;
  if constexpr (N == 1)
    asm("v_add_f32 %0, %1, %1 row_ror:1" : "=v"(r) : "v"(x));
  else if constexpr (N == 2)
    asm("v_add_f32 %0, %1, %1 row_ror:2" : "=v"(r) : "v"(x));
  else if constexpr (N == 4)
    asm("v_add_f32 %0, %1, %1 row_ror:4" : "=v"(r) : "v"(x));
  else
    asm("v_add_f32 %0, %1, %1 row_ror:8" : "=v"(r) : "v"(x));
  return r;
}
__device__ __forceinline__ void mix_lo(float& acc, uint_ a, uint_ b) {
  asm("v_fma_mix_f32 %0, %1, %2, %0 op_sel:[0,0,0] op_sel_hi:[1,1,0]"
      : "+v"(acc) : "v"(a), "v"(b));
}
__device__ __forceinline__ void mix_hi(float& acc, uint_ a, uint_ b) {
  asm("v_fma_mix_f32 %0, %1, %2, %0 op_sel:[1,1,0] op_sel_hi:[1,1,0]"
      : "+v"(acc) : "v"(a), "v"(b));
}
__device__ __forceinline__ void pk_fma(uint_& acc, uint_ x, uint_ c) {
  asm("v_pk_fma_f16 %0, %1, %2, %0" : "+v"(acc) : "v"(x), "v"(c));
}
__device__ __forceinline__ uint_ pk_mul(uint_ a, uint_ b) {
  uint_ r;
  asm("v_pk_mul_f16 %0, %1, %2" : "=v"(r) : "v"(a), "v"(b));
  return r;
}

// ---------------------------------------------------------------------------
// Dispatch 1 (mega): blocks 0..1023 = transpose x f32 -> xbt f16;
// blocks 1024..1056 = prep (M frags f16 * log2e, packed wpos, Wv frags f16).
// A-frag layout (16x16x32): lane=(i&15)+16*((k>>3)&3), reg=k&7.
// ---------------------------------------------------------------------------
__global__ __launch_bounds__(256) void mega_kernel(
    const float* __restrict__ x, u16* __restrict__ xbt,
    const float* __restrict__ w_q, const float* __restrict__ w_k,
    const float* __restrict__ w_v,
    const float* __restrict__ row_emb, const float* __restrict__ col_emb,
    const float* __restrict__ mix_emb,
    u16* __restrict__ MF, u16* __restrict__ WF, uint_* __restrict__ wpk) {
  if (blockIdx.x < 1024) {
    __shared__ float tile[64][129];
    int by = blockIdx.x;
    int b = by >> 7, y = by & 127;
    const float* xp = x + (size_t)b * (CIN_ * H_ * W_) + (size_t)y * W_;
    #pragma unroll
    for (int it = 0; it < 32; ++it) {
      int idx = threadIdx.x + it * 256;
      int c = idx >> 7, xw = idx & 127;
      tile[c][xw] = xp[(size_t)c * (H_ * W_) + xw];
    }
    __syncthreads();
    uint_* dst = (uint_*)(xbt + ((size_t)(b * H_ + y)) * (W_ * 64));
    #pragma unroll
    for (int it = 0; it < 16; ++it) {
      int idx = threadIdx.x + it * 256;   // = xw*32 + cp
      int xw = idx >> 5, cp = idx & 31;
      dst[idx] = cvt_pk_u(tile[2 * cp][xw], tile[2 * cp + 1][xw]);
    }
  } else {
    int pb = blockIdx.x - 1024;   // 0..32
    if (pb < 16) {
      // M[a][c] = sum_o w_q[o,a] * w_k[o,c], scaled by log2(e) for exp2 path
      int idx = pb * 256 + threadIdx.x;  // 0..4095
      int a = idx >> 6, c = idx & 63;
      float acc = 0.f;
      #pragma unroll 8
      for (int o = 0; o < 128; ++o)
        acc = fmaf(w_q[o * 64 + a], w_k[o * 64 + c], acc);
      int m = c >> 4, lr = c & 15;
      int ks = a >> 5, q = (a >> 3) & 3, jr = a & 7;
      int off = ((ks * 4 + m) * 64 + (lr + 16 * q)) * 8 + jr;
      MF[off] = f2h_bits(acc * 1.44269504f);
    } else if (pb == 16) {
      int p = threadIdx.x;
      if (p < 25) {
        int i = p / 5, j = p % 5;
        float a0 = 0.f, a1 = 0.f;
        for (int c = 0; c < 128; ++c) {
          float rc = row_emb[c * 5 + i] + col_emb[c * 5 + j];
          a0 = fmaf(rc, mix_emb[c * 2 + 0], a0);
          a1 = fmaf(rc, mix_emb[c * 2 + 1], a1);
        }
        float mx = fmaxf(a0, a1);
        float e0 = __expf(a0 - mx), e1 = __expf(a1 - mx);
        float inv = 1.f / (e0 + e1);
        wpk[p]      = cvt_pk_u(e0 * inv, e0 * inv);
        wpk[32 + p] = cvt_pk_u(e1 * inv, e1 * inv);
      }
    } else {
      // Wv[c][k] = w_v[c*128+k]; A-frag (i=c, k), 8 m-tiles (c=128)
      int t = (pb - 17) * 256 + threadIdx.x;  // 0..4095
      #pragma unroll
      for (int e = 0; e < 4; ++e) {
        int elem = t * 4 + e;            // = c*128 + k
        int c = elem >> 7, k = elem & 127;
        int m = c >> 4, lr = c & 15;
        int ks = k >> 5, q = (k >> 3) & 3, j = k & 7;
        int off = ((ks * 8 + m) * 64 + (lr + 16 * q)) * 8 + j;
        WF[off] = f2h_bits(w_v[elem]);
      }
    }
  }
}

// ---------------------------------------------------------------------------
// Dispatch 2 (fused stage + U + attn + out GEMM), byte-identical to R16.
// Launched 3x this round (idempotent) so its counters surface in top-5.
// ---------------------------------------------------------------------------
__global__ __launch_bounds__(512, 4) void attn_out_kernel(
    const u16* __restrict__ xbt, const u16* __restrict__ MF,
    const uint_* __restrict__ wpk, const u16* __restrict__ WF,
    float* __restrict__ out) {
  __shared__ u16 Xl[5 * 67 * 64];   // [row][col][ch], ch-stride 64 u16 = 128 B
  __shared__ union {
    float Ul[32][68];               // row stride 272 B
    u16   Gl[32][136];
  } GU;

  int tid = threadIdx.x;
  int wave = tid >> 6, lane = tid & 63;
  int lr = lane & 15, q = lane >> 4;

  int bid = (int)blockIdx.x;
  int swz = (bid & 7) * 128 + (bid >> 3);   // XCD owns one batch image
  int pos0 = swz * 32;

  int b = pos0 >> 12;
  int ho0 = (pos0 >> 6) & 63;
  int y0 = 2 * ho0, x0base = 2 * (pos0 & 63);

  // ----- Stage x-window -> Xl, ZERO for OOB (handles all padding) -----
  {
    int sl = tid & 15;
    int pi0 = tid >> 4;
    const u16* xbb = xbt + (size_t)b * (H_ * W_ * 64);
    #pragma unroll
    for (int it = 0; it < 11; ++it) {
      int pi = it * 32 + pi0;       // 0..351, need 0..334
      if (pi < 335) {
        int row = pi / 67;
        int col = pi - row * 67;
        int yr = y0 + row - 2, xr = x0base + col - 2;
        bool oob = ((unsigned)yr >= (unsigned)H_) | ((unsigned)xr >= (unsigned)W_);
        int yc = min(max(yr, 0), H_ - 1);
        int xc = min(max(xr, 0), W_ - 1);
        uint2 d = *(const uint2*)(xbb + ((size_t)yc * W_ + xc) * 64 + sl * 4);
        if (oob) { d.x = 0u; d.y = 0u; }
        *(uint2*)(&Xl[pi * 64 + sl * 4]) = d;
      }
    }
  }

  // ----- Phase 0: U = M^T xq (f16 M * log2e) -----
  {
    int pt = wave >> 2, mm = wave & 3;      // pos-tile (0,1), m-tile (0..3)
    int pu = pos0 + pt * 16 + lr;
    int bu = pu >> 12, hou = (pu >> 6) & 63, wou = pu & 63;
    const u16* xq = xbt + ((size_t)(bu * H_ + 2 * hou) * W_ + 2 * wou) * 64;
    f4 ua = (f4)0.f;
    #pragma unroll
    for (int ks = 0; ks < 2; ++ks) {
      f16x8 bb = *reinterpret_cast<const f16x8*>(xq + ks * 32 + q * 8);
      f16x8 ah = *reinterpret_cast<const f16x8*>(
          MF + ((ks * 4 + mm) * 64 + lane) * 8);
      ua = __builtin_amdgcn_mfma_f32_16x16x32_f16(ah, bb, ua, 0, 0, 0);
    }
    #pragma unroll
    for (int r = 0; r < 4; ++r)
      GU.Ul[pt * 16 + lr][mm * 16 + q * 4 + r] = ua[r];
  }
  __syncthreads();

  // ----- Phase 1: attention, stage-split for 25-wide ILP -----
  {
    int r = wave * 4 + q;              // local position 0..31
    const u16* xl0 = &Xl[(2 * r) * 64 + lr * 4];

    f4 u = *reinterpret_cast<const f4*>(&GU.Ul[r][lr * 4]);
    uint_ u01 = cvt_pk_u(u.x, u.y);
    uint_ u23 = cvt_pk_u(u.z, u.w);

    uint2 d[25];
    #pragma unroll
    for (int p = 0; p < 25; ++p) {
      const int dy = p / 5, dx = p % 5;
      d[p] = *(const uint2*)(xl0 + (dy * 67 + dx) * 64);
    }

    float sp[25];
    #pragma unroll
    for (int p = 0; p < 25; ++p) {
      float s = -0.5f;               // 16-lane sum -> -8 exp2 bias
      mix_lo(s, d[p].x, u01);
      mix_hi(s, d[p].x, u01);
      mix_lo(s, d[p].y, u23);
      mix_hi(s, d[p].y, u23);
      sp[p] = s;
    }

    #pragma unroll
    for (int p = 0; p < 25; ++p) sp[p] = ror_add<1>(sp[p]);
    #pragma unroll
    for (int p = 0; p < 25; ++p) sp[p] = ror_add<2>(sp[p]);
    #pragma unroll
    for (int p = 0; p < 25; ++p) sp[p] = ror_add<4>(sp[p]);
    #pragma unroll
    for (int p = 0; p < 25; ++p) sp[p] = ror_add<8>(sp[p]);

    float Z0 = 0.f, Z1 = 0.f, Z2 = 0.f, Z3 = 0.f;
    #pragma unroll
    for (int p = 0; p < 25; ++p) {
      sp[p] = __builtin_amdgcn_exp2f(sp[p]);
      if ((p & 3) == 0) Z0 += sp[p];
      else if ((p & 3) == 1) Z1 += sp[p];
      else if ((p & 3) == 2) Z2 += sp[p];
      else Z3 += sp[p];
    }

    uint_ g0a = 0u, g0b = 0u, g1a = 0u, g1b = 0u;
    #pragma unroll
    for (int p = 0; p < 25; ++p) {
      uint_ epk = cvt_pk_u(sp[p], sp[p]);
      uint_ c0 = pk_mul(epk, wpk[p]);
      uint_ c1 = pk_mul(epk, wpk[32 + p]);
      pk_fma(g0a, d[p].x, c0);
      pk_fma(g0b, d[p].y, c0);
      pk_fma(g1a, d[p].x, c1);
      pk_fma(g1b, d[p].y, c1);
    }
    float rZ = 1.f / ((Z0 + Z1) + (Z2 + Z3));
    uint_ rZpk = cvt_pk_u(rZ, rZ);

    uint2 w0, w1;
    w0.x = pk_mul(g0a, rZpk); w0.y = pk_mul(g0b, rZpk);
    w1.x = pk_mul(g1a, rZpk); w1.y = pk_mul(g1b, rZpk);
    *(uint2*)&GU.Gl[r][lr * 4] = w0;
    *(uint2*)&GU.Gl[r][64 + lr * 4] = w1;
  }

  __syncthreads();

  // ----- Phase 2: out GEMM (f16 Wv frags) -----
  {
    f4 acc0 = (f4)0.f, acc1 = (f4)0.f;
    #pragma unroll
    for (int ks = 0; ks < 4; ++ks) {
      f16x8 b0 = *reinterpret_cast<const f16x8*>(&GU.Gl[lr][ks * 32 + q * 8]);
      f16x8 b1 = *reinterpret_cast<const f16x8*>(&GU.Gl[16 + lr][ks * 32 + q * 8]);
      f16x8 ah = *reinterpret_cast<const f16x8*>(
          WF + ((ks * 8 + wave) * 64 + lane) * 8);
      acc0 = __builtin_amdgcn_mfma_f32_16x16x32_f16(ah, b0, acc0, 0, 0, 0);
      acc1 = __builtin_amdgcn_mfma_f32_16x16x32_f16(ah, b1, acc1, 0, 0, 0);
    }
    int bb = pos0 >> 12;
    int hw0 = pos0 & 4095;
    float* op = out + (size_t)bb * (OC_ * HO_ * WO_) + hw0;
    #pragma unroll
    for (int rr = 0; rr < 4; ++rr) {
      int c = wave * 16 + q * 4 + rr;
      op[(size_t)c * 4096 + lr] = acc0[rr];
      op[(size_t)c * 4096 + 16 + lr] = acc1[rr];
    }
  }
}

// ---------------------------------------------------------------------------
extern "C" void kernel_launch(void* const* d_in, const int* in_sizes, int n_in,
                              void* d_out, int out_size, void* d_ws, size_t ws_size,
                              hipStream_t stream) {
  const float* x       = (const float*)d_in[0];
  const float* w_q     = (const float*)d_in[1];
  const float* w_k     = (const float*)d_in[2];
  const float* w_v     = (const float*)d_in[3];
  const float* row_emb = (const float*)d_in[4];
  const float* col_emb = (const float*)d_in[5];
  const float* mix_emb = (const float*)d_in[6];
  float* out = (float*)d_out;

  float* ws   = (float*)d_ws;
  u16*   xbt  = (u16*)(ws + XBT_OFF);
  u16*   MF   = (u16*)(ws + MF_OFF);
  u16*   WF   = (u16*)(ws + WF_OFF);
  uint_* wpk  = (uint_*)(ws + WPOS_OFF);

  mega_kernel<<<1024 + 33, 256, 0, stream>>>(x, xbt, w_q, w_k, w_v, row_emb,
                                             col_emb, mix_emb, MF, WF, wpk);
  // 3x idempotent launches: identical output, surfaces per-dispatch counters
  // (inst 1 = xbt-cold, inst 2/3 = L2/L3-warm -> memory vs compute split).
  attn_out_kernel<<<NPOS / 32, 512, 0, stream>>>(xbt, MF, wpk, WF, out);
  attn_out_kernel<<<NPOS / 32, 512, 0, stream>>>(xbt, MF, wpk, WF, out);
  attn_out_kernel<<<NPOS / 32, 512, 0, stream>>>(xbt, MF, wpk, WF, out);
}

// Round 18
// 35.246 us; speedup vs baseline: 1.9563x; 1.9563x over previous
//
#include <hip/hip_runtime.h>

typedef unsigned int   uint_;
typedef unsigned short u16;
typedef _Float16 f16;
typedef __attribute__((ext_vector_type(8))) _Float16 f16x8;  // MFMA A/B frag
typedef __attribute__((ext_vector_type(2))) __fp16 h2;       // builtin half2
typedef __attribute__((ext_vector_type(4))) float f4;

// Problem constants
#define B_    8
#define CIN_  64
#define H_    128
#define W_    128
#define OC_   128
#define HO_   64
#define WO_   64
#define NPOS  (B_ * HO_ * WO_)   // 32768

// ws layout (float offsets)
#define XBT_OFF  0          // f16 x_bt (B,H,W,64) = 4194304 floats
#define MF_OFF   4194304    // u16[4096]  (f16 M frags, pre-scaled by log2e)
#define WF_OFF   4196352    // u16[16384] (f16 Wv frags)
#define WPOS_OFF 4204544    // packed h2: wp0[25] @ +0, wp1[25] @ +32 (u32 each)

// ---------------------------------------------------------------------------
// helpers
// ---------------------------------------------------------------------------
__device__ __forceinline__ u16 f2h_bits(float x) {
  return __builtin_bit_cast(u16, (f16)x);
}
__device__ __forceinline__ uint_ cvt_pk_u(float lo, float hi) {
  return __builtin_bit_cast(uint_, __builtin_amdgcn_cvt_pkrtz(lo, hi));
}
template <int N>
__device__ __forceinline__ float ror_add(float x) {
  float r;
  if constexpr (N == 1)
    asm("v_add_f32 %0, %1, %1 row_ror:1" : "=v"(r) : "v"(x));
  else if constexpr (N == 2)
    asm("v_add_f32 %0, %1, %1 row_ror:2" : "=v"(r) : "v"(x));
  else if constexpr (N == 4)
    asm("v_add_f32 %0, %1, %1 row_ror:4" : "=v"(r) : "v"(x));
  else
    asm("v_add_f32 %0, %1, %1 row_ror:8" : "=v"(r) : "v"(x));
  return r;
}
__device__ __forceinline__ void mix_lo(float& acc, uint_ a, uint_ b) {
  asm("v_fma_mix_f32 %0, %1, %2, %0 op_sel:[0,0,0] op_sel_hi:[1,1,0]"
      : "+v"(acc) : "v"(a), "v"(b));
}
__device__ __forceinline__ void mix_hi(float& acc, uint_ a, uint_ b) {
  asm("v_fma_mix_f32 %0, %1, %2, %0 op_sel:[1,1,0] op_sel_hi:[1,1,0]"
      : "+v"(acc) : "v"(a), "v"(b));
}
__device__ __forceinline__ void pk_fma(uint_& acc, uint_ x, uint_ c) {
  asm("v_pk_fma_f16 %0, %1, %2, %0" : "+v"(acc) : "v"(x), "v"(c));
}
__device__ __forceinline__ uint_ pk_mul(uint_ a, uint_ b) {
  uint_ r;
  asm("v_pk_mul_f16 %0, %1, %2" : "=v"(r) : "v"(a), "v"(b));
  return r;
}

// ---------------------------------------------------------------------------
// Dispatch 1 (mega): blocks 0..1023 = transpose x f32 -> xbt f16, with
// VECTORIZED global I/O (float4 reads, uint2 writes); blocks 1024..1056 =
// prep (M frags f16 * log2e, packed wpos, Wv frags f16).
// ---------------------------------------------------------------------------
__global__ __launch_bounds__(256) void mega_kernel(
    const float* __restrict__ x, u16* __restrict__ xbt,
    const float* __restrict__ w_q, const float* __restrict__ w_k,
    const float* __restrict__ w_v,
    const float* __restrict__ row_emb, const float* __restrict__ col_emb,
    const float* __restrict__ mix_emb,
    u16* __restrict__ MF, u16* __restrict__ WF, uint_* __restrict__ wpk) {
  if (blockIdx.x < 1024) {
    __shared__ float tile[64][129];
    int by = blockIdx.x;
    int b = by >> 7, y = by & 127;
    const float* xp = x + (size_t)b * (CIN_ * H_ * W_) + (size_t)y * W_;
    // loads: 8 iters of float4 (coalesced 512B per 32 lanes)
    #pragma unroll
    for (int it = 0; it < 8; ++it) {
      int idx2 = threadIdx.x + it * 256;     // 0..2047
      int c = idx2 >> 5, xq4 = idx2 & 31;
      float4 v = *reinterpret_cast<const float4*>(
          xp + (size_t)c * (H_ * W_) + 4 * xq4);
      tile[c][4 * xq4 + 0] = v.x;
      tile[c][4 * xq4 + 1] = v.y;
      tile[c][4 * xq4 + 2] = v.z;
      tile[c][4 * xq4 + 3] = v.w;
    }
    __syncthreads();
    // stores: 8 iters of uint2 (4 channels packed, coalesced 512B/wave)
    uint2* dst2 = (uint2*)(xbt + ((size_t)(b * H_ + y)) * (W_ * 64));
    #pragma unroll
    for (int it = 0; it < 8; ++it) {
      int idx2 = threadIdx.x + it * 256;     // 0..2047
      int xw = idx2 >> 4, cp2 = idx2 & 15;   // pixel, 4-ch group
      uint2 w;
      w.x = cvt_pk_u(tile[4 * cp2 + 0][xw], tile[4 * cp2 + 1][xw]);
      w.y = cvt_pk_u(tile[4 * cp2 + 2][xw], tile[4 * cp2 + 3][xw]);
      dst2[xw * 16 + cp2] = w;
    }
  } else {
    int pb = blockIdx.x - 1024;   // 0..32
    if (pb < 16) {
      // M[a][c] = sum_o w_q[o,a] * w_k[o,c], scaled by log2(e) for exp2 path
      int idx = pb * 256 + threadIdx.x;  // 0..4095
      int a = idx >> 6, c = idx & 63;
      float acc = 0.f;
      #pragma unroll 8
      for (int o = 0; o < 128; ++o)
        acc = fmaf(w_q[o * 64 + a], w_k[o * 64 + c], acc);
      int m = c >> 4, lr = c & 15;
      int ks = a >> 5, q = (a >> 3) & 3, jr = a & 7;
      int off = ((ks * 4 + m) * 64 + (lr + 16 * q)) * 8 + jr;
      MF[off] = f2h_bits(acc * 1.44269504f);
    } else if (pb == 16) {
      int p = threadIdx.x;
      if (p < 25) {
        int i = p / 5, j = p % 5;
        float a0 = 0.f, a1 = 0.f;
        for (int c = 0; c < 128; ++c) {
          float rc = row_emb[c * 5 + i] + col_emb[c * 5 + j];
          a0 = fmaf(rc, mix_emb[c * 2 + 0], a0);
          a1 = fmaf(rc, mix_emb[c * 2 + 1], a1);
        }
        float mx = fmaxf(a0, a1);
        float e0 = __expf(a0 - mx), e1 = __expf(a1 - mx);
        float inv = 1.f / (e0 + e1);
        wpk[p]      = cvt_pk_u(e0 * inv, e0 * inv);
        wpk[32 + p] = cvt_pk_u(e1 * inv, e1 * inv);
      }
    } else {
      // Wv[c][k] = w_v[c*128+k]; A-frag (i=c, k), 8 m-tiles (c=128)
      int t = (pb - 17) * 256 + threadIdx.x;  // 0..4095
      #pragma unroll
      for (int e = 0; e < 4; ++e) {
        int elem = t * 4 + e;            // = c*128 + k
        int c = elem >> 7, k = elem & 127;
        int m = c >> 4, lr = c & 15;
        int ks = k >> 5, q = (k >> 3) & 3, j = k & 7;
        int off = ((ks * 8 + m) * 64 + (lr + 16 * q)) * 8 + j;
        WF[off] = f2h_bits(w_v[elem]);
      }
    }
  }
}

// ---------------------------------------------------------------------------
// Dispatch 2 (fused stage + U + attn + out GEMM), 16-pos blocks for
// residency: 256 thr (4 waves), LDS = Xl 5x35x64 u16 (21.9K) + union Ul/Gl
// (4.25K) = 26.2K -> 6 blocks/CU resident (launch_bounds(256,6), VGPR<=85;
// simple tap loop fits). Cross-block overlap hides per-block phase latency
// (R16: 2 blocks/CU -> 12us stall despite 4.7us VALU issue).
// grid = NPOS/16 = 2048, XCD-swizzled (XCD owns one image).
// ---------------------------------------------------------------------------
__global__ __launch_bounds__(256, 6) void attn_out_kernel(
    const u16* __restrict__ xbt, const u16* __restrict__ MF,
    const uint_* __restrict__ wpk, const u16* __restrict__ WF,
    float* __restrict__ out) {
  __shared__ u16 Xl[5 * 35 * 64];   // [row][col][ch], ch-stride 64 u16
  __shared__ union {
    float Ul[16][68];
    u16   Gl[16][136];
  } GU;

  int tid = threadIdx.x;
  int wave = tid >> 6, lane = tid & 63;
  int lr = lane & 15, q = lane >> 4;

  int bid = (int)blockIdx.x;
  int swz = (bid & 7) * 256 + (bid >> 3);   // XCD owns one batch image
  int pos0 = swz * 16;

  int b = pos0 >> 12;
  int ho0 = (pos0 >> 6) & 63;
  int y0 = 2 * ho0, x0base = 2 * (pos0 & 63);

  // ----- Stage x-window (5 rows x 35 cols x 64ch) -> Xl, ZERO OOB -----
  {
    int sl = tid & 15;            // 8-byte ch-chunk
    int pi0 = tid >> 4;           // 0..15
    const u16* xbb = xbt + (size_t)b * (H_ * W_ * 64);
    #pragma unroll
    for (int it = 0; it < 11; ++it) {
      int pi = it * 16 + pi0;     // 0..175, need 0..174
      if (pi < 175) {
        int row = pi / 35;
        int col = pi - row * 35;
        int yr = y0 + row - 2, xr = x0base + col - 2;
        bool oob = ((unsigned)yr >= (unsigned)H_) | ((unsigned)xr >= (unsigned)W_);
        int yc = min(max(yr, 0), H_ - 1);
        int xc = min(max(xr, 0), W_ - 1);
        uint2 d = *(const uint2*)(xbb + ((size_t)yc * W_ + xc) * 64 + sl * 4);
        if (oob) { d.x = 0u; d.y = 0u; }
        *(uint2*)(&Xl[pi * 64 + sl * 4]) = d;
      }
    }
  }

  // ----- Phase 0: U = M^T xq; wave = m-tile (4 m-tiles, one 16-pos tile) ---
  {
    int mm = wave;                          // m-tile 0..3
    int pu = pos0 + lr;                     // B-frag col j = lr
    int bu = pu >> 12, hou = (pu >> 6) & 63, wou = pu & 63;
    const u16* xq = xbt + ((size_t)(bu * H_ + 2 * hou) * W_ + 2 * wou) * 64;
    f4 ua = (f4)0.f;
    #pragma unroll
    for (int ks = 0; ks < 2; ++ks) {
      f16x8 bb = *reinterpret_cast<const f16x8*>(xq + ks * 32 + q * 8);
      f16x8 ah = *reinterpret_cast<const f16x8*>(
          MF + ((ks * 4 + mm) * 64 + lane) * 8);
      ua = __builtin_amdgcn_mfma_f32_16x16x32_f16(ah, bb, ua, 0, 0, 0);
    }
    #pragma unroll
    for (int r = 0; r < 4; ++r)
      GU.Ul[lr][mm * 16 + q * 4 + r] = ua[r];
  }
  __syncthreads();

  // ----- Phase 1: attention, simple 18-op tap loop (R16: ILP-split ≡) -----
  {
    int r = wave * 4 + q;              // local position 0..15
    const u16* xl0 = &Xl[(2 * r) * 64 + lr * 4];

    f4 u = *reinterpret_cast<const f4*>(&GU.Ul[r][lr * 4]);
    uint_ u01 = cvt_pk_u(u.x, u.y);
    uint_ u23 = cvt_pk_u(u.z, u.w);

    float Z0 = 0.f, Z1 = 0.f;
    uint_ g0a = 0u, g0b = 0u, g1a = 0u, g1b = 0u;

    #pragma unroll
    for (int p = 0; p < 25; ++p) {
      const int dy = p / 5, dx = p % 5;
      uint2 d = *(const uint2*)(xl0 + (dy * 35 + dx) * 64);
      float sp = -0.5f;                // 16-lane sum -> -8 exp2 bias
      mix_lo(sp, d.x, u01);
      mix_hi(sp, d.x, u01);
      mix_lo(sp, d.y, u23);
      mix_hi(sp, d.y, u23);
      sp = ror_add<1>(sp);
      sp = ror_add<2>(sp);
      sp = ror_add<4>(sp);
      sp = ror_add<8>(sp);             // full row-16 sum (64 ch) - 8
      float e = __builtin_amdgcn_exp2f(sp);
      if (p & 1) Z1 += e; else Z0 += e;
      uint_ epk = cvt_pk_u(e, e);
      uint_ c0 = pk_mul(epk, wpk[p]);
      uint_ c1 = pk_mul(epk, wpk[32 + p]);
      pk_fma(g0a, d.x, c0);
      pk_fma(g0b, d.y, c0);
      pk_fma(g1a, d.x, c1);
      pk_fma(g1b, d.y, c1);
    }
    float rZ = 1.f / (Z0 + Z1);
    uint_ rZpk = cvt_pk_u(rZ, rZ);

    uint2 w0, w1;
    w0.x = pk_mul(g0a, rZpk); w0.y = pk_mul(g0b, rZpk);
    w1.x = pk_mul(g1a, rZpk); w1.y = pk_mul(g1b, rZpk);
    *(uint2*)&GU.Gl[r][lr * 4] = w0;
    *(uint2*)&GU.Gl[r][64 + lr * 4] = w1;
  }

  __syncthreads();

  // ----- Phase 2: out GEMM; each wave does m-tiles (wave) and (wave+4) ----
  {
    int bb = pos0 >> 12;
    int hw0 = pos0 & 4095;
    float* op = out + (size_t)bb * (OC_ * HO_ * WO_) + hw0;
    #pragma unroll
    for (int t = 0; t < 2; ++t) {
      int mm = wave + t * 4;
      f4 acc = (f4)0.f;
      #pragma unroll
      for (int ks = 0; ks < 4; ++ks) {
        f16x8 b0 = *reinterpret_cast<const f16x8*>(&GU.Gl[lr][ks * 32 + q * 8]);
        f16x8 ah = *reinterpret_cast<const f16x8*>(
            WF + ((ks * 8 + mm) * 64 + lane) * 8);
        acc = __builtin_amdgcn_mfma_f32_16x16x32_f16(ah, b0, acc, 0, 0, 0);
      }
      #pragma unroll
      for (int rr = 0; rr < 4; ++rr) {
        int c = mm * 16 + q * 4 + rr;
        op[(size_t)c * 4096 + lr] = acc[rr];
      }
    }
  }
}

// ---------------------------------------------------------------------------
extern "C" void kernel_launch(void* const* d_in, const int* in_sizes, int n_in,
                              void* d_out, int out_size, void* d_ws, size_t ws_size,
                              hipStream_t stream) {
  const float* x       = (const float*)d_in[0];
  const float* w_q     = (const float*)d_in[1];
  const float* w_k     = (const float*)d_in[2];
  const float* w_v     = (const float*)d_in[3];
  const float* row_emb = (const float*)d_in[4];
  const float* col_emb = (const float*)d_in[5];
  const float* mix_emb = (const float*)d_in[6];
  float* out = (float*)d_out;

  float* ws   = (float*)d_ws;
  u16*   xbt  = (u16*)(ws + XBT_OFF);
  u16*   MF   = (u16*)(ws + MF_OFF);
  u16*   WF   = (u16*)(ws + WF_OFF);
  uint_* wpk  = (uint_*)(ws + WPOS_OFF);

  mega_kernel<<<1024 + 33, 256, 0, stream>>>(x, xbt, w_q, w_k, w_v, row_emb,
                                             col_emb, mix_emb, MF, WF, wpk);
  attn_out_kernel<<<NPOS / 16, 256, 0, stream>>>(xbt, MF, wpk, WF, out);
}